// Round 1
// baseline (505.264 us; speedup 1.0000x reference)
//
#include <hip/hip_runtime.h>
#include <math.h>

constexpr int Bn = 256, Sn = 128, Hn = 256;
constexpr int GRP = 16;

// ---------------- setup: branch kernels k_i[h,tau] = irfft(w_i[h,:]) ----------------
// kT layout: [24][H]  slots: n=3 -> 0..2, n=5 -> 3..7, n=7 -> 8..14, n=9 -> 15..23
__global__ void k_setup(const float* __restrict__ w3, const float* __restrict__ w5,
                        const float* __restrict__ w7, const float* __restrict__ w9,
                        float* __restrict__ kT) {
  int t = blockIdx.x * blockDim.x + threadIdx.x;
  if (t >= 24 * Hn) return;
  int slot = t >> 8, h = t & 255;
  int n, base;
  const float* w;
  if (slot < 3)       { n = 3; base = 0;  w = w3; }
  else if (slot < 8)  { n = 5; base = 3;  w = w5; }
  else if (slot < 15) { n = 7; base = 8;  w = w7; }
  else                { n = 9; base = 15; w = w9; }
  int tau = slot - base;
  int F = (n + 1) / 2;
  // weight layout (1,H,F,1,2)
  float acc = w[(h * F) * 2];  // DC real (imag of DC cannot affect real output)
  for (int f = 1; f < F; f++) {
    float wr = w[(h * F + f) * 2 + 0];
    float wi = w[(h * F + f) * 2 + 1];
    int ft = (f * tau) % n;  // exact periodic reduction
    float ang = 6.28318530717958647692f * (float)ft / (float)n;
    float sv, cv;
    __sincosf(ang, &sv, &cv);
    acc += 2.f * (wr * cv - wi * sv);
  }
  kT[slot * Hn + h] = acc / (float)n;
}

// ---------------- setup: fft-branch circular kernel c[h,d] = irfft(cw[:,h]) ----------------
// cT layout: [128][H]  (d-major so lane reads over h are coalesced)
__global__ void c_setup(const float* __restrict__ cw, float* __restrict__ cT) {
  int t = blockIdx.x * blockDim.x + threadIdx.x;
  if (t >= Sn * Hn) return;
  int d = t >> 8, h = t & 255;
  // cw layout (1, 65, H, 2)
  float acc = cw[(0 * Hn + h) * 2 + 0] + ((d & 1) ? -1.f : 1.f) * cw[(64 * Hn + h) * 2 + 0];
  for (int k = 1; k < 64; k++) {
    float wr = cw[(k * Hn + h) * 2 + 0];
    float wi = cw[(k * Hn + h) * 2 + 1];
    int kd = (k * d) & 127;  // exact mod-128 reduction keeps __sincosf arg in [0,2pi)
    float ang = 6.28318530717958647692f * (float)kd * (1.f / 128.f);
    float sv, cv;
    __sincosf(ang, &sv, &cv);
    acc += 2.f * (wr * cv - wi * sv);
  }
  cT[d * Hn + h] = acc * (1.f / 128.f);
}

// ---------------- STFT branch accumulation (taps + overlap-add geometry) ----------------
template <int N, int BASE>
__device__ __attribute__((always_inline)) void branch_accum(
    const float (&xw)[32], const float (&kreg)[24], int s0, bool edge, float (&z)[GRP]) {
  constexpr int PAD = (N - 1) / 2;
  #pragma unroll
  for (int i = 0; i < GRP; i++) z[i] = 0.f;
  #pragma unroll
  for (int j = -(N - 1); j <= N - 1; j++) {
    const int m = (((-j) % N) + N) % N;   // folded at compile time under unroll
    const float kc = kreg[BASE + m];
    if (!edge) {
      // interior: cnt = N-|j|, env = N
      const float ka = kc * ((float)(N - (j < 0 ? -j : j)) * (1.f / (float)N));
      #pragma unroll
      for (int i = 0; i < GRP; i++) z[i] = fmaf(ka, xw[8 + i + j], z[i]);
    } else {
      #pragma unroll
      for (int i = 0; i < GRP; i++) {
        int s = s0 + i, l = s + PAD;
        int tlo = max(0, max(l - Sn + 1, -j));
        int thi = min(N - 1, min(l, N - 1 - j));
        int cnt = max(0, thi - tlo + 1);
        int elo = max(0, l - Sn + 1), ehi = min(N - 1, l);
        float env = (float)(ehi - elo + 1);
        z[i] = fmaf(kc * ((float)cnt / env), xw[8 + i + j], z[i]);
      }
    }
  }
}

// ---------------- fused main kernel: one block per batch b ----------------
__global__ __launch_bounds__(512) void stft_main(
    const float* __restrict__ x, const float* __restrict__ cT,
    const float* __restrict__ kT, const float* __restrict__ lnw,
    const float* __restrict__ lnb, const float* __restrict__ alphap,
    float* __restrict__ out) {
  __shared__ float xs[Sn][Hn];          // 131072 B
  __shared__ float red[2][GRP][4][2];   // 1024 B  cross-wave LN partials

  const int t = threadIdx.x;
  const int h = t & 255;
  const int sg = t >> 8;       // which s-half (0: s 0..63, 1: s 64..127)
  const int wv = h >> 6;       // wave within half
  const int lane = h & 63;
  const int b = blockIdx.x;

  // stage x[b] into LDS (coalesced float4, layout identical to global)
  {
    const float4* xg = (const float4*)(x + (size_t)b * Sn * Hn);
    float4* xl = (float4*)(&xs[0][0]);
    #pragma unroll
    for (int c = 0; c < 16; c++) xl[c * 512 + t] = xg[c * 512 + t];
  }
  const float alpha = alphap[0];
  const float wgt = lnw[h], bia = lnb[h];
  float kreg[24];
  #pragma unroll
  for (int q = 0; q < 24; q++) kreg[q] = kT[q * Hn + h];
  __syncthreads();

  // layernorm over h for 16 s-rows at once (in-place on q)
  auto reduce_ln = [&](float (&q)[GRP]) {
    float sum[GRP], sq[GRP];
    #pragma unroll
    for (int i = 0; i < GRP; i++) { sum[i] = q[i]; sq[i] = q[i] * q[i]; }
    #pragma unroll
    for (int o = 32; o > 0; o >>= 1) {
      #pragma unroll
      for (int i = 0; i < GRP; i++) {
        sum[i] += __shfl_xor(sum[i], o, 64);
        sq[i]  += __shfl_xor(sq[i],  o, 64);
      }
    }
    if (lane == 0) {
      #pragma unroll
      for (int i = 0; i < GRP; i++) { red[sg][i][wv][0] = sum[i]; red[sg][i][wv][1] = sq[i]; }
    }
    __syncthreads();
    #pragma unroll
    for (int i = 0; i < GRP; i++) {
      float ts = red[sg][i][0][0] + red[sg][i][1][0] + red[sg][i][2][0] + red[sg][i][3][0];
      float tq = red[sg][i][0][1] + red[sg][i][1][1] + red[sg][i][2][1] + red[sg][i][3][1];
      float u = ts * (1.f / 256.f);
      float var = tq * (1.f / 256.f) - u * u;
      float inv = 1.f / sqrtf(var + 1e-12f);
      q[i] = fmaf((q[i] - u) * inv, wgt, bia);
    }
    __syncthreads();
  };

  for (int g = 0; g < 4; g++) {
    const int s0 = sg * 64 + g * GRP;
    const bool edge = (s0 == 0) || (s0 + GRP == Sn);

    // x window rows s0-8 .. s0+23 (zero-padded like reference's u)
    float xw[32];
    #pragma unroll
    for (int k = 0; k < 32; k++) {
      int r = s0 - 8 + k;
      xw[k] = (r >= 0 && r < Sn) ? xs[r][h] : 0.f;
    }

    // ---- four STFT branches, each layernormed then summed ----
    float semb[GRP];
    {
      float z[GRP];
      branch_accum<3, 0>(xw, kreg, s0, edge, z);
      reduce_ln(z);
      #pragma unroll
      for (int i = 0; i < GRP; i++) semb[i] = z[i];
      branch_accum<5, 3>(xw, kreg, s0, edge, z);
      reduce_ln(z);
      #pragma unroll
      for (int i = 0; i < GRP; i++) semb[i] += z[i];
      branch_accum<7, 8>(xw, kreg, s0, edge, z);
      reduce_ln(z);
      #pragma unroll
      for (int i = 0; i < GRP; i++) semb[i] += z[i];
      branch_accum<9, 15>(xw, kreg, s0, edge, z);
      reduce_ln(z);
      #pragma unroll
      for (int i = 0; i < GRP; i++) semb[i] += z[i];
    }

    // ---- global-fft branch: circular conv, block-Toeplitz 16x16 tiles ----
    float ff[GRP];
    #pragma unroll
    for (int i = 0; i < GRP; i++) ff[i] = 0.f;
    #pragma unroll
    for (int rt = 0; rt < 8; rt++) {
      const int r0 = rt * 16;
      const int dbase = (s0 - r0) & 127;
      float cd[31];
      #pragma unroll
      for (int k = 0; k < 31; k++)
        cd[k] = cT[((dbase + k - 15) & 127) * Hn + h];
      float xr[16];
      #pragma unroll
      for (int j = 0; j < 16; j++) xr[j] = xs[r0 + j][h];
      #pragma unroll
      for (int i = 0; i < GRP; i++) {
        #pragma unroll
        for (int j = 0; j < 16; j++)
          ff[i] = fmaf(cd[i - j + 15], xr[j], ff[i]);
      }
    }
    reduce_ln(ff);

    // ---- mix + residual + final LN + store ----
    float fin[GRP];
    #pragma unroll
    for (int i = 0; i < GRP; i++)
      fin[i] = alpha * semb[i] + (1.f - alpha) * ff[i] + xs[s0 + i][h];
    reduce_ln(fin);
    #pragma unroll
    for (int i = 0; i < GRP; i++)
      out[((size_t)b * Sn + (s0 + i)) * Hn + h] = fin[i];
  }
}

extern "C" void kernel_launch(void* const* d_in, const int* in_sizes, int n_in,
                              void* d_out, int out_size, void* d_ws, size_t ws_size,
                              hipStream_t stream) {
  const float* x  = (const float*)d_in[0];
  const float* w3 = (const float*)d_in[1];
  const float* w5 = (const float*)d_in[2];
  const float* w7 = (const float*)d_in[3];
  const float* w9 = (const float*)d_in[4];
  const float* cw = (const float*)d_in[5];
  const float* al = (const float*)d_in[6];
  const float* lw = (const float*)d_in[7];
  const float* lb = (const float*)d_in[8];
  float* out = (float*)d_out;

  float* cT = (float*)d_ws;        // 128*256 floats
  float* kT = cT + Sn * Hn;        // 24*256 floats

  hipLaunchKernelGGL(k_setup, dim3(24), dim3(256), 0, stream, w3, w5, w7, w9, kT);
  hipLaunchKernelGGL(c_setup, dim3(Sn), dim3(256), 0, stream, cw, cT);
  hipLaunchKernelGGL(stft_main, dim3(Bn), dim3(512), 0, stream, x, cT, kT, lw, lb, al, out);
}